// Round 21
// baseline (122.602 us; speedup 1.0000x reference)
//
#include <hip/hip_runtime.h>
#include <hip/hip_bf16.h>
#include <math.h>

#define EPSF 1e-8f
typedef __attribute__((ext_vector_type(8))) short short8;
typedef __attribute__((ext_vector_type(4))) short s4v;
typedef __attribute__((ext_vector_type(4))) float f32x4;

__device__ __forceinline__ float wred_sum(float v) {
#pragma unroll
  for (int o = 32; o > 0; o >>= 1) v += __shfl_down(v, o, 64);
  return v;
}

static __device__ __forceinline__ unsigned short f2bf(float f) {
  __hip_bfloat16 h = __float2bfloat16(f);
  return *reinterpret_cast<unsigned short*>(&h);
}
static __device__ __forceinline__ float bf2f(unsigned short u) {
  unsigned int v = ((unsigned int)u) << 16;
  float f;
  __builtin_memcpy(&f, &v, 4);
  return f;
}

// ---------------- K0: merged {zero accumulators + weights->bf16 + mask lengths}
__global__ __launch_bounds__(256) void k_zc(
    const float* __restrict__ attn_w, const float* __restrict__ ctx_w,
    const int* __restrict__ mask, unsigned short* __restrict__ awb,
    unsigned short* __restrict__ cwb, float* __restrict__ zp,
    float* __restrict__ Lbuf, int nz4, int C, int D, int B, int T) {
  int i = blockIdx.x * 256 + threadIdx.x;
  int DC = D * C;
  if (i < DC) {
    int d = i / C, c = i % C;
    awb[i] = f2bf(attn_w[(size_t)d * 3 * C + c]);
  } else if (i < 2 * DC) {
    int j = i - DC;
    cwb[j] = f2bf(ctx_w[j]);
  }
  if (i < nz4)
    *reinterpret_cast<float4*>(zp + (size_t)i * 4) = (float4){0.f, 0.f, 0.f, 0.f};
  if (blockIdx.x < B) {
    int b = blockIdx.x;
    const int* mr = mask + (size_t)b * T;
    float sl = 0.f;
    for (int t = threadIdx.x; t < T; t += 256) sl += (float)mr[t];
    __shared__ float rl[4];
    sl = wred_sum(sl);
    if ((threadIdx.x & 63) == 0) rl[threadIdx.x >> 6] = sl;
    __syncthreads();
    if (threadIdx.x == 0) Lbuf[b] = rl[0] + rl[1] + rl[2] + rl[3];
  }
}

// ---------------- K1: FUSED {masked stats + bf16 transpose + xbT write + GEMM1-raw}
// Grid (T/64, B) = 1024, r14-gemm1 skeleton (2 barriers/chunk, reg-prefetch).
// Per 64-c chunk: x fp32 (coalesced along t, L3-hot) -> stats + transpose-at-
// write -> As; awb -> Bs; per-chunk stats flush (c changes each chunk); MFMA;
// xbT chunk write-out from As. Epilogue writes RAW alpha (pre-bias/tanh) into
// alphaT -- bias2 is the only sequential dep and it folds into k_tanh.
// Deletes gemm1's separate 64 MB xbT read. LDS 27.6 KB -> 4 blocks/CU.
__global__ __launch_bounds__(256) void k_fwd1(
    const float* __restrict__ x, const int* __restrict__ mask,
    const unsigned short* __restrict__ awb, float* __restrict__ sums,
    unsigned short* __restrict__ xbT, unsigned short* __restrict__ alphaT,
    int C, int T, int D) {
  int b = blockIdx.y;
  int t0 = blockIdx.x * 64;
  int tid = threadIdx.x;
  int w = tid >> 6, lane = tid & 63;
  int l15 = lane & 15, g = lane >> 4;
  __shared__ unsigned short As[64][72];   // transposed x chunk [t][c] bf16
  __shared__ unsigned short Bs[128][72];  // awb chunk [d][c]

  int cr = tid >> 2, q = tid & 3;  // x-load/transpose role
  int dr = tid >> 1, h = tid & 1;  // Bs staging role

  const int* mr = mask + (size_t)b * T;
  float mv[16];
#pragma unroll
  for (int ss = 0; ss < 4; ss++)
#pragma unroll
    for (int j = 0; j < 4; j++) {
      int t = t0 + (q + 4 * ss) * 4 + j;
      mv[ss * 4 + j] = (t < T && mr[t] != 0) ? 1.f : 0.f;
    }

  f32x4 acc[4][2];
#pragma unroll
  for (int i = 0; i < 4; i++)
#pragma unroll
    for (int j = 0; j < 2; j++) acc[i][j] = (f32x4){0.f, 0.f, 0.f, 0.f};

  float4 rx[4];
  short8 rb[4];

#define LOADX(cc0)                                                             \
  {                                                                            \
    const float* xr_ = x + ((size_t)b * C + (cc0) + cr) * T;                   \
    _Pragma("unroll")                                                          \
    for (int ss = 0; ss < 4; ss++) {                                           \
      int t = t0 + (q + 4 * ss) * 4;                                           \
      if (t + 3 < T) {                                                         \
        rx[ss] = *reinterpret_cast<const float4*>(&xr_[t]);                    \
      } else {                                                                 \
        rx[ss].x = (t < T) ? xr_[t] : 0.f;                                     \
        rx[ss].y = (t + 1 < T) ? xr_[t + 1] : 0.f;                             \
        rx[ss].z = (t + 2 < T) ? xr_[t + 2] : 0.f;                             \
        rx[ss].w = (t + 3 < T) ? xr_[t + 3] : 0.f;                             \
      }                                                                        \
    }                                                                          \
  }

#define LOADB(cc0)                                                             \
  {                                                                            \
    size_t base_ = (size_t)dr * C + (cc0) + h * 32;                            \
    _Pragma("unroll")                                                          \
    for (int qq = 0; qq < 4; qq++)                                             \
      rb[qq] = *reinterpret_cast<const short8*>(&awb[base_ + qq * 8]);         \
  }

  LOADX(0);
  LOADB(0);

  for (int c0 = 0; c0 < C; c0 += 64) {
    __syncthreads();  // prev compute done reading As/Bs
    // consume rx: stats + transpose-at-write into As (bf16)
    float s1 = 0.f, s2 = 0.f;
#pragma unroll
    for (int ss = 0; ss < 4; ss++) {
      float4 v = rx[ss];
      s1 += mv[ss*4+0]*v.x + mv[ss*4+1]*v.y + mv[ss*4+2]*v.z + mv[ss*4+3]*v.w;
      s2 += mv[ss*4+0]*v.x*v.x + mv[ss*4+1]*v.y*v.y + mv[ss*4+2]*v.z*v.z + mv[ss*4+3]*v.w*v.w;
      int tl = (q + 4 * ss) * 4;
      As[tl + 0][cr] = f2bf(v.x);
      As[tl + 1][cr] = f2bf(v.y);
      As[tl + 2][cr] = f2bf(v.z);
      As[tl + 3][cr] = f2bf(v.w);
    }
#pragma unroll
    for (int qq = 0; qq < 4; qq++)
      *reinterpret_cast<short8*>(&Bs[dr][h * 32 + qq * 8]) = rb[qq];
    // per-chunk stats flush (this chunk's channel = c0 + cr)
    s1 += __shfl_down(s1, 2, 4); s1 += __shfl_down(s1, 1, 4);
    s2 += __shfl_down(s2, 2, 4); s2 += __shfl_down(s2, 1, 4);
    if (q == 0) {
      float* sp = &sums[((size_t)b * C + c0 + cr) * 2];
      atomicAdd(sp, s1);
      atomicAdd(sp + 1, s2);
    }
    // prefetch next chunk (in flight through barrier + MFMA phase)
    if (c0 + 64 < C) {
      LOADX(c0 + 64);
      LOADB(c0 + 64);
    }
    __syncthreads();  // As/Bs visible
#pragma unroll
    for (int ks = 0; ks < 2; ks++) {
      short8 a[4], bb[2];
#pragma unroll
      for (int tf = 0; tf < 4; tf++)
        a[tf] = *reinterpret_cast<const short8*>(&As[tf * 16 + l15][ks * 32 + g * 8]);
#pragma unroll
      for (int df = 0; df < 2; df++)
        bb[df] = *reinterpret_cast<const short8*>(&Bs[w * 32 + df * 16 + l15][ks * 32 + g * 8]);
#pragma unroll
      for (int tf = 0; tf < 4; tf++)
#pragma unroll
        for (int df = 0; df < 2; df++)
          acc[tf][df] = __builtin_amdgcn_mfma_f32_16x16x32_bf16(a[tf], bb[df], acc[tf][df], 0, 0, 0);
    }
    // xbT chunk write-out (row-contiguous LDS reads + coalesced global store)
    {
      int t = t0 + cr;
      if (t < T) {
        unsigned short* dst = &xbT[((size_t)b * T + t) * C + c0 + q * 16];
        *reinterpret_cast<short8*>(dst) =
            *reinterpret_cast<const short8*>(&As[cr][q * 16]);
        *reinterpret_cast<short8*>(dst + 8) =
            *reinterpret_cast<const short8*>(&As[cr][q * 16 + 8]);
      }
    }
  }
#undef LOADX
#undef LOADB

  // epilogue: RAW alpha (pre-bias/tanh); k_tanh finishes in place
#pragma unroll
  for (int df = 0; df < 2; df++) {
    int d = w * 32 + df * 16 + l15;
#pragma unroll
    for (int tf = 0; tf < 4; tf++)
#pragma unroll
      for (int r = 0; r < 4; r++) {
        int t = t0 + tf * 16 + g * 4 + r;
        if (t < T)
          alphaT[((size_t)b * T + t) * D + d] = f2bf(acc[tf][df][r]);
      }
  }
}

// ---------------- K2: bias2 dot, wave-per-d (grid B*D/4, no LDS, no barriers)
__global__ __launch_bounds__(256) void k_bias2f(
    const float* __restrict__ attn_w, const float* __restrict__ attn_b,
    const float* __restrict__ sums, const float* __restrict__ Lbuf,
    float* __restrict__ bias2, int C, int D) {
  int nb = D >> 2;
  int b = blockIdx.x / nb;
  int d = (blockIdx.x % nb) * 4 + (threadIdx.x >> 6);
  int lane = threadIdx.x & 63;
  float L = fmaxf(Lbuf[b], 1.f);
  const float* wr = attn_w + (size_t)d * 3 * C;
  float s = 0.f;
  for (int c = lane; c < C; c += 64) {
    float s1 = sums[((size_t)b * C + c) * 2];
    float s2 = sums[((size_t)b * C + c) * 2 + 1];
    float mu = s1 / L;
    float var = s2 / L - mu * mu;
    float sd = sqrtf(fmaxf(var, EPSF));
    s += wr[C + c] * mu + wr[2 * C + c] * sd;
  }
  s = wred_sum(s);
  if (lane == 0) bias2[(size_t)b * D + d] = attn_b[d] + s;
}

// ---------------- K3: in-place alphaT = tanh(raw + bias2[b][d]) elementwise
__global__ __launch_bounds__(256) void k_tanh(
    unsigned short* __restrict__ alphaT, const float* __restrict__ bias2,
    int T, int D, int total8) {
  int i = blockIdx.x * 256 + threadIdx.x;
  if (i >= total8) return;
  size_t base = (size_t)i * 8;
  int d0 = (int)(base % D);
  size_t bt = base / D;
  int b = (int)(bt / T);
  const float* bp = &bias2[(size_t)b * D + d0];
  short8 raw = *reinterpret_cast<const short8*>(&alphaT[base]);
  unsigned short o[8];
#pragma unroll
  for (int j = 0; j < 8; j++)
    o[j] = f2bf(tanhf(bf2f((unsigned short)raw[j]) + bp[j]));
  *reinterpret_cast<short8*>(&alphaT[base]) = *reinterpret_cast<short8*>(&o[0]);
}

// ---------------- K4: fused MFMA GEMM2 + masked exp + partial pooled sums
// r17's validated config: depth-2 Bl pipeline + per-lane xv register prefetch,
// t-chunk 512 (8 subtiles/block), grid 1024 = exactly 4/CU.
// ctx_b omitted (softmax shift-invariance).
__global__ __launch_bounds__(256) void k_pool2(
    const unsigned short* __restrict__ alphaT, const unsigned short* __restrict__ cwb,
    const unsigned short* __restrict__ xbT, const int* __restrict__ mask,
    float* __restrict__ Sacc, int C, int T, int D) {
  int b = blockIdx.z;
  int c0 = blockIdx.y * 64;
  int ch0 = blockIdx.x * 512;
  int tid = threadIdx.x;
  int w = tid >> 6, lane = tid & 63, l15 = lane & 15, g = lane >> 4;
  __shared__ unsigned short Bl[2][64][136];  // alphaT tiles [t][d]

  short8 a[4];
#pragma unroll
  for (int ks = 0; ks < 4; ks++)
    a[ks] = *reinterpret_cast<const short8*>(
        &cwb[(size_t)(c0 + w * 16 + l15) * D + ks * 32 + g * 8]);
  int cbase = c0 + w * 16 + g * 4;
  float S0[4] = {0.f, 0.f, 0.f, 0.f};
  float S1[4] = {0.f, 0.f, 0.f, 0.f};
  float S2[4] = {0.f, 0.f, 0.f, 0.f};

  const int* mr = mask + (size_t)b * T;
  int srow = tid >> 2, sq = tid & 3;

  int rem = T - ch0;
  int ntt = rem >= 512 ? 8 : (rem + 63) >> 6;

  short8 pa0, pa1, pa2, pa3;
  s4v xv[2][4];
  const unsigned short* xbb = &xbT[(size_t)b * T * C];

#define LOADSUB(st)                                                            \
  {                                                                            \
    int trow = ch0 + (st) * 64 + srow;                                         \
    pa0 = pa1 = pa2 = pa3 = (short8){};                                        \
    if (trow < T) {                                                            \
      const unsigned short* sa = &alphaT[((size_t)b * T + trow) * D + sq * 32];\
      pa0 = *reinterpret_cast<const short8*>(sa);                              \
      pa1 = *reinterpret_cast<const short8*>(sa + 8);                          \
      pa2 = *reinterpret_cast<const short8*>(sa + 16);                         \
      pa3 = *reinterpret_cast<const short8*>(sa + 24);                         \
    }                                                                          \
  }

#define WRITESUB(bufi)                                                         \
  {                                                                            \
    *reinterpret_cast<short8*>(&Bl[bufi][srow][sq * 32]) = pa0;                \
    *reinterpret_cast<short8*>(&Bl[bufi][srow][sq * 32 + 8]) = pa1;            \
    *reinterpret_cast<short8*>(&Bl[bufi][srow][sq * 32 + 16]) = pa2;           \
    *reinterpret_cast<short8*>(&Bl[bufi][srow][sq * 32 + 24]) = pa3;           \
  }

#define GXV(pi, st)                                                            \
  {                                                                            \
    _Pragma("unroll")                                                          \
    for (int tf_ = 0; tf_ < 4; tf_++) {                                        \
      int t_ = ch0 + (st) * 64 + tf_ * 16 + l15;                               \
      int tc_ = t_ < T ? t_ : T - 1;                                           \
      xv[pi][tf_] = *reinterpret_cast<const s4v*>(&xbb[(size_t)tc_ * C + cbase]);\
    }                                                                          \
  }

  LOADSUB(0);
  WRITESUB(0);
  if (ntt > 1) LOADSUB(1);
  GXV(0, 0);
  if (ntt > 1) GXV(1, 1);
  __syncthreads();

#pragma unroll
  for (int k = 0; k < 8; k++) {
    if (k >= ntt) break;
    int buf = k & 1;
    if (k + 1 < ntt) {
      WRITESUB((k + 1) & 1);
      if (k + 2 < ntt) LOADSUB(k + 2);
    }
    int t0 = ch0 + k * 64;
#pragma unroll
    for (int tf = 0; tf < 4; tf++) {
      f32x4 p = (f32x4){0.f, 0.f, 0.f, 0.f};
#pragma unroll
      for (int ks = 0; ks < 4; ks++) {
        short8 bb = *reinterpret_cast<const short8*>(
            &Bl[buf][tf * 16 + l15][ks * 32 + g * 8]);
        p = __builtin_amdgcn_mfma_f32_16x16x32_bf16(a[ks], bb, p, 0, 0, 0);
      }
      int t = t0 + tf * 16 + l15;
      bool valid = (t < T) && (mr[t < T ? t : 0] != 0);
#pragma unroll
      for (int r = 0; r < 4; r++) {
        float e = valid ? __expf(p[r]) : 0.f;  // logits tanh-bounded: no max-sub
        float xvf = bf2f((unsigned short)xv[buf][tf][r]);
        S0[r] += e; S1[r] += e * xvf; S2[r] += e * xvf * xvf;
      }
    }
    if (k + 2 < ntt) GXV(buf, k + 2);
    __syncthreads();
  }
#undef LOADSUB
#undef WRITESUB
#undef GXV

#pragma unroll
  for (int r = 0; r < 4; r++) {
#pragma unroll
    for (int o = 1; o < 16; o <<= 1) {
      S0[r] += __shfl_xor(S0[r], o, 16);
      S1[r] += __shfl_xor(S1[r], o, 16);
      S2[r] += __shfl_xor(S2[r], o, 16);
    }
  }
  if (l15 == 0) {
#pragma unroll
    for (int r = 0; r < 4; r++) {
      float* sp = &Sacc[((size_t)b * C + cbase + r) * 3];
      atomicAdd(sp, S0[r]);
      atomicAdd(sp + 1, S1[r]);
      atomicAdd(sp + 2, S2[r]);
    }
  }
}

// ---------------- K5: finalize pooled mean/std
__global__ __launch_bounds__(256) void k_out(
    const float* __restrict__ Sacc, float* __restrict__ out, int C) {
  int b = blockIdx.x;
  for (int c = threadIdx.x; c < C; c += 256) {
    float S0 = Sacc[((size_t)b * C + c) * 3];
    float S1 = Sacc[((size_t)b * C + c) * 3 + 1];
    float S2 = Sacc[((size_t)b * C + c) * 3 + 2];
    float pm = S1 / S0;
    float var = S2 / S0 - pm * pm;
    out[(size_t)b * 2 * C + c] = pm;
    out[(size_t)b * 2 * C + C + c] = sqrtf(fmaxf(var, EPSF));
  }
}

extern "C" void kernel_launch(void* const* d_in, const int* in_sizes, int n_in,
                              void* d_out, int out_size, void* d_ws, size_t ws_size,
                              hipStream_t stream) {
  const float* x = (const float*)d_in[0];
  const float* attn_w = (const float*)d_in[1];
  const float* attn_b = (const float*)d_in[2];
  const float* ctx_w = (const float*)d_in[3];
  const int* mask = (const int*)d_in[5];
  float* out = (float*)d_out;

  int D = in_sizes[2];         // 128
  int C = in_sizes[4];         // 512
  int B = out_size / (2 * C);  // 32
  int T = in_sizes[5] / B;     // 2000

  // workspace layout (~82.5 MB)
  unsigned short* awb = (unsigned short*)d_ws;        // D*C bf16
  unsigned short* cwb = awb + (size_t)D * C;          // C*D bf16
  float* bias2 = (float*)(cwb + (size_t)C * D);       // B*D
  float* Lbuf = bias2 + (size_t)B * D;                // B
  float* sums = Lbuf + B;                             // B*C*2 (zeroed)
  float* Sacc = sums + (size_t)B * C * 2;             // B*C*3 (zeroed)
  unsigned short* xbT = (unsigned short*)(Sacc + (size_t)B * C * 3);  // B*T*C bf16
  unsigned short* alphaT = xbT + (size_t)B * T * C;                   // B*T*D bf16

  int nz4 = (B * C * 5 + 3) / 4;  // sums + Sacc, in float4 units
  int zcn = 2 * D * C;
  if (nz4 > zcn) zcn = nz4;
  k_zc<<<(zcn + 255) / 256, 256, 0, stream>>>(
      attn_w, ctx_w, mask, awb, cwb, sums, Lbuf, nz4, C, D, B, T);
  k_fwd1<<<dim3((T + 63) / 64, B), 256, 0, stream>>>(
      x, mask, awb, sums, xbT, alphaT, C, T, D);
  k_bias2f<<<B * (D / 4), 256, 0, stream>>>(attn_w, attn_b, sums, Lbuf, bias2, C, D);
  int total8 = (int)((size_t)B * T * D / 8);
  k_tanh<<<(total8 + 255) / 256, 256, 0, stream>>>(alphaT, bias2, T, D, total8);
  k_pool2<<<dim3((T + 511) / 512, C / 64, B), 256, 0, stream>>>(
      alphaT, cwb, xbT, mask, Sacc, C, T, D);
  k_out<<<B, 256, 0, stream>>>(Sacc, out, C);
}

// Round 22
// 117.099 us; speedup vs baseline: 1.0470x; 1.0470x over previous
//
#include <hip/hip_runtime.h>
#include <hip/hip_bf16.h>
#include <math.h>

#define EPSF 1e-8f
typedef __attribute__((ext_vector_type(8))) short short8;
typedef __attribute__((ext_vector_type(4))) short s4v;
typedef __attribute__((ext_vector_type(4))) float f32x4;

__device__ __forceinline__ float wred_sum(float v) {
#pragma unroll
  for (int o = 32; o > 0; o >>= 1) v += __shfl_down(v, o, 64);
  return v;
}

static __device__ __forceinline__ unsigned short f2bf(float f) {
  __hip_bfloat16 h = __float2bfloat16(f);
  return *reinterpret_cast<unsigned short*>(&h);
}
static __device__ __forceinline__ float bf2f(unsigned short u) {
  unsigned int v = ((unsigned int)u) << 16;
  float f;
  __builtin_memcpy(&f, &v, 4);
  return f;
}

// ---------------- K0: merged {zero accumulators + weights->bf16 + mask lengths}
__global__ __launch_bounds__(256) void k_zc(
    const float* __restrict__ attn_w, const float* __restrict__ ctx_w,
    const int* __restrict__ mask, unsigned short* __restrict__ awb,
    unsigned short* __restrict__ cwb, float* __restrict__ zp,
    float* __restrict__ Lbuf, int nz4, int C, int D, int B, int T) {
  int i = blockIdx.x * 256 + threadIdx.x;
  int DC = D * C;
  if (i < DC) {
    int d = i / C, c = i % C;
    awb[i] = f2bf(attn_w[(size_t)d * 3 * C + c]);
  } else if (i < 2 * DC) {
    int j = i - DC;
    cwb[j] = f2bf(ctx_w[j]);
  }
  if (i < nz4)
    *reinterpret_cast<float4*>(zp + (size_t)i * 4) = (float4){0.f, 0.f, 0.f, 0.f};
  if (blockIdx.x < B) {
    int b = blockIdx.x;
    const int* mr = mask + (size_t)b * T;
    float sl = 0.f;
    for (int t = threadIdx.x; t < T; t += 256) sl += (float)mr[t];
    __shared__ float rl[4];
    sl = wred_sum(sl);
    if ((threadIdx.x & 63) == 0) rl[threadIdx.x >> 6] = sl;
    __syncthreads();
    if (threadIdx.x == 0) Lbuf[b] = rl[0] + rl[1] + rl[2] + rl[3];
  }
}

// ---------------- K1: masked partial sums + transpose, 4 t-tiles per block,
// REGISTER-PREFETCHED (validated round 20, best config 117.4 us).
__global__ __launch_bounds__(256) void k_ms_tr(
    const float* __restrict__ x, const int* __restrict__ mask,
    float* __restrict__ sums, unsigned short* __restrict__ xbT, int C, int T) {
  int b = blockIdx.z, c0 = blockIdx.x * 64, tbase = blockIdx.y * 256;
  int tid = threadIdx.x;
  int row = tid >> 2, q = tid & 3;
  __shared__ unsigned short Xb[64][72];  // [t-local][c-local] bf16, pitch 144B
  const float* xr = x + ((size_t)b * C + c0 + row) * T;
  const int* mr = mask + (size_t)b * T;
  float s1 = 0.f, s2 = 0.f;

  int rem = T - tbase;
  int ntt = rem >= 256 ? 4 : (rem + 63) >> 6;

  float4 rx[4];
  int4 rm[4];

#define LOADT(st)                                                              \
  {                                                                            \
    int t0_ = tbase + (st) * 64;                                               \
    _Pragma("unroll")                                                          \
    for (int ss = 0; ss < 4; ss++) {                                           \
      int t = t0_ + (q + 4 * ss) * 4;                                          \
      if (t + 3 < T) {                                                         \
        rx[ss] = *reinterpret_cast<const float4*>(&xr[t]);                     \
        rm[ss] = *reinterpret_cast<const int4*>(&mr[t]);                       \
      } else {                                                                 \
        rx[ss].x = (t < T) ? xr[t] : 0.f;     rm[ss].x = (t < T) ? mr[t] : 0;  \
        rx[ss].y = (t+1 < T) ? xr[t+1] : 0.f; rm[ss].y = (t+1 < T) ? mr[t+1] : 0;\
        rx[ss].z = (t+2 < T) ? xr[t+2] : 0.f; rm[ss].z = (t+2 < T) ? mr[t+2] : 0;\
        rx[ss].w = (t+3 < T) ? xr[t+3] : 0.f; rm[ss].w = (t+3 < T) ? mr[t+3] : 0;\
      }                                                                        \
    }                                                                          \
  }

  LOADT(0);

#pragma unroll
  for (int tt = 0; tt < 4; tt++) {
    if (tt >= ntt) break;
    int t0 = tbase + tt * 64;
#pragma unroll
    for (int ss = 0; ss < 4; ss++) {
      float4 v = rx[ss];
      float m0 = (float)rm[ss].x, m1 = (float)rm[ss].y;
      float m2 = (float)rm[ss].z, m3 = (float)rm[ss].w;
      s1 += m0 * v.x + m1 * v.y + m2 * v.z + m3 * v.w;
      s2 += m0 * v.x * v.x + m1 * v.y * v.y + m2 * v.z * v.z + m3 * v.w * v.w;
      int tl = (q + 4 * ss) * 4;
      Xb[tl + 0][row] = f2bf(v.x);
      Xb[tl + 1][row] = f2bf(v.y);
      Xb[tl + 2][row] = f2bf(v.z);
      Xb[tl + 3][row] = f2bf(v.w);
    }
    if (tt + 1 < ntt) LOADT(tt + 1);
    __syncthreads();  // Xb visible
    {
      int trow = tid >> 2;
      int t = t0 + trow;
      if (t < T) {
        unsigned short* dst = &xbT[((size_t)b * T + t) * C + c0 + q * 16];
        *reinterpret_cast<short8*>(dst) =
            *reinterpret_cast<const short8*>(&Xb[trow][q * 16]);
        *reinterpret_cast<short8*>(dst + 8) =
            *reinterpret_cast<const short8*>(&Xb[trow][q * 16 + 8]);
      }
    }
    if (tt + 1 < ntt) __syncthreads();  // LDS reads done before next overwrite
  }
#undef LOADT

  s1 += __shfl_down(s1, 2, 4); s1 += __shfl_down(s1, 1, 4);
  s2 += __shfl_down(s2, 2, 4); s2 += __shfl_down(s2, 1, 4);
  if (q == 0) {
    float* sp = &sums[((size_t)b * C + c0 + row) * 2];
    atomicAdd(sp, s1);
    atomicAdd(sp + 1, s2);
  }
}

// ---------------- K2: bias2 dot, wave-per-d (grid B*D/4, no LDS, no barriers)
__global__ __launch_bounds__(256) void k_bias2f(
    const float* __restrict__ attn_w, const float* __restrict__ attn_b,
    const float* __restrict__ sums, const float* __restrict__ Lbuf,
    float* __restrict__ bias2, int C, int D) {
  int nb = D >> 2;  // blocks per batch = D/4
  int b = blockIdx.x / nb;
  int d = (blockIdx.x % nb) * 4 + (threadIdx.x >> 6);
  int lane = threadIdx.x & 63;
  float L = fmaxf(Lbuf[b], 1.f);
  const float* wr = attn_w + (size_t)d * 3 * C;
  float s = 0.f;
  for (int c = lane; c < C; c += 64) {
    float s1 = sums[((size_t)b * C + c) * 2];
    float s2 = sums[((size_t)b * C + c) * 2 + 1];
    float mu = s1 / L;
    float var = s2 / L - mu * mu;
    float sd = sqrtf(fmaxf(var, EPSF));
    s += wr[C + c] * mu + wr[2 * C + c] * sd;
  }
  s = wred_sum(s);
  if (lane == 0) bias2[(size_t)b * D + d] = attn_b[d] + s;
}

// ---------------- K3: MFMA GEMM1, 64t x 128d tile (validated round 14)
__global__ __launch_bounds__(256) void k_gemm1(
    const unsigned short* __restrict__ xbT, const unsigned short* __restrict__ awb,
    const float* __restrict__ bias2, unsigned short* __restrict__ alphaT,
    int C, int T, int D) {
  int b = blockIdx.y;
  int t0 = blockIdx.x * 64;
  int tid = threadIdx.x;
  int w = tid >> 6, lane = tid & 63;
  int l15 = lane & 15, g = lane >> 4;
  __shared__ unsigned short As[64][72];   // [t][c] pitch 144B
  __shared__ unsigned short Bs[128][72];  // [d][c]
  f32x4 acc[4][2];
#pragma unroll
  for (int i = 0; i < 4; i++)
#pragma unroll
    for (int j = 0; j < 2; j++) acc[i][j] = (f32x4){0.f, 0.f, 0.f, 0.f};

  int ar = tid >> 2, aq = tid & 3;
  int dr = tid >> 1, h = tid & 1;
  bool okA = (t0 + ar) < T;
  size_t rowA = ((size_t)b * T + t0 + ar) * C + aq * 16;
  size_t rowB = (size_t)dr * C + h * 32;

  short8 ra[2], rb[4];
  ra[0] = okA ? *reinterpret_cast<const short8*>(&xbT[rowA]) : (short8){};
  ra[1] = okA ? *reinterpret_cast<const short8*>(&xbT[rowA + 8]) : (short8){};
#pragma unroll
  for (int qq = 0; qq < 4; qq++)
    rb[qq] = *reinterpret_cast<const short8*>(&awb[rowB + qq * 8]);

  for (int c0 = 0; c0 < C; c0 += 64) {
    __syncthreads();
    *reinterpret_cast<short8*>(&As[ar][aq * 16]) = ra[0];
    *reinterpret_cast<short8*>(&As[ar][aq * 16 + 8]) = ra[1];
#pragma unroll
    for (int qq = 0; qq < 4; qq++)
      *reinterpret_cast<short8*>(&Bs[dr][h * 32 + qq * 8]) = rb[qq];
    if (c0 + 64 < C) {
      size_t nA = rowA + c0 + 64, nB = rowB + c0 + 64;
      ra[0] = okA ? *reinterpret_cast<const short8*>(&xbT[nA]) : (short8){};
      ra[1] = okA ? *reinterpret_cast<const short8*>(&xbT[nA + 8]) : (short8){};
#pragma unroll
      for (int qq = 0; qq < 4; qq++)
        rb[qq] = *reinterpret_cast<const short8*>(&awb[nB + qq * 8]);
    }
    __syncthreads();
#pragma unroll
    for (int ks = 0; ks < 2; ks++) {
      short8 a[4], bb[2];
#pragma unroll
      for (int tf = 0; tf < 4; tf++)
        a[tf] = *reinterpret_cast<const short8*>(&As[tf * 16 + l15][ks * 32 + g * 8]);
#pragma unroll
      for (int df = 0; df < 2; df++)
        bb[df] = *reinterpret_cast<const short8*>(&Bs[w * 32 + df * 16 + l15][ks * 32 + g * 8]);
#pragma unroll
      for (int tf = 0; tf < 4; tf++)
#pragma unroll
        for (int df = 0; df < 2; df++)
          acc[tf][df] = __builtin_amdgcn_mfma_f32_16x16x32_bf16(a[tf], bb[df], acc[tf][df], 0, 0, 0);
    }
  }
#pragma unroll
  for (int df = 0; df < 2; df++) {
    int d = w * 32 + df * 16 + l15;
    float bias = bias2[(size_t)b * D + d];
#pragma unroll
    for (int tf = 0; tf < 4; tf++)
#pragma unroll
      for (int r = 0; r < 4; r++) {
        int t = t0 + tf * 16 + g * 4 + r;
        if (t < T)
          alphaT[((size_t)b * T + t) * D + d] = f2bf(tanhf(bias + acc[tf][df][r]));
      }
  }
}

// ---------------- K4: fused MFMA GEMM2 + masked exp + partial pooled sums
// r17's validated config: depth-2 Bl pipeline + per-lane xv register prefetch,
// t-chunk 512 (8 subtiles/block), grid 1024 = exactly 4/CU.
// ctx_b omitted (softmax shift-invariance).
__global__ __launch_bounds__(256) void k_pool2(
    const unsigned short* __restrict__ alphaT, const unsigned short* __restrict__ cwb,
    const unsigned short* __restrict__ xbT, const int* __restrict__ mask,
    float* __restrict__ Sacc, int C, int T, int D) {
  int b = blockIdx.z;
  int c0 = blockIdx.y * 64;
  int ch0 = blockIdx.x * 512;
  int tid = threadIdx.x;
  int w = tid >> 6, lane = tid & 63, l15 = lane & 15, g = lane >> 4;
  __shared__ unsigned short Bl[2][64][136];  // alphaT tiles [t][d]

  short8 a[4];
#pragma unroll
  for (int ks = 0; ks < 4; ks++)
    a[ks] = *reinterpret_cast<const short8*>(
        &cwb[(size_t)(c0 + w * 16 + l15) * D + ks * 32 + g * 8]);
  int cbase = c0 + w * 16 + g * 4;
  float S0[4] = {0.f, 0.f, 0.f, 0.f};
  float S1[4] = {0.f, 0.f, 0.f, 0.f};
  float S2[4] = {0.f, 0.f, 0.f, 0.f};

  const int* mr = mask + (size_t)b * T;
  int srow = tid >> 2, sq = tid & 3;

  int rem = T - ch0;
  int ntt = rem >= 512 ? 8 : (rem + 63) >> 6;

  short8 pa0, pa1, pa2, pa3;
  s4v xv[2][4];
  const unsigned short* xbb = &xbT[(size_t)b * T * C];

#define LOADSUB(st)                                                            \
  {                                                                            \
    int trow = ch0 + (st) * 64 + srow;                                         \
    pa0 = pa1 = pa2 = pa3 = (short8){};                                        \
    if (trow < T) {                                                            \
      const unsigned short* sa = &alphaT[((size_t)b * T + trow) * D + sq * 32];\
      pa0 = *reinterpret_cast<const short8*>(sa);                              \
      pa1 = *reinterpret_cast<const short8*>(sa + 8);                          \
      pa2 = *reinterpret_cast<const short8*>(sa + 16);                         \
      pa3 = *reinterpret_cast<const short8*>(sa + 24);                         \
    }                                                                          \
  }

#define WRITESUB(bufi)                                                         \
  {                                                                            \
    *reinterpret_cast<short8*>(&Bl[bufi][srow][sq * 32]) = pa0;                \
    *reinterpret_cast<short8*>(&Bl[bufi][srow][sq * 32 + 8]) = pa1;            \
    *reinterpret_cast<short8*>(&Bl[bufi][srow][sq * 32 + 16]) = pa2;           \
    *reinterpret_cast<short8*>(&Bl[bufi][srow][sq * 32 + 24]) = pa3;           \
  }

#define GXV(pi, st)                                                            \
  {                                                                            \
    _Pragma("unroll")                                                          \
    for (int tf_ = 0; tf_ < 4; tf_++) {                                        \
      int t_ = ch0 + (st) * 64 + tf_ * 16 + l15;                               \
      int tc_ = t_ < T ? t_ : T - 1;                                           \
      xv[pi][tf_] = *reinterpret_cast<const s4v*>(&xbb[(size_t)tc_ * C + cbase]);\
    }                                                                          \
  }

  // prologue: buf0 <- subtile 0; alphaT regs <- subtile 1; xv <- subtiles 0,1
  LOADSUB(0);
  WRITESUB(0);
  if (ntt > 1) LOADSUB(1);
  GXV(0, 0);
  if (ntt > 1) GXV(1, 1);
  __syncthreads();  // buf0 visible

#pragma unroll
  for (int k = 0; k < 8; k++) {
    if (k >= ntt) break;
    int buf = k & 1;
    if (k + 1 < ntt) {
      WRITESUB((k + 1) & 1);            // waits on loads issued at iter k-1
      if (k + 2 < ntt) LOADSUB(k + 2);  // in flight through next compute
    }
    int t0 = ch0 + k * 64;
#pragma unroll
    for (int tf = 0; tf < 4; tf++) {
      f32x4 p = (f32x4){0.f, 0.f, 0.f, 0.f};
#pragma unroll
      for (int ks = 0; ks < 4; ks++) {
        short8 bb = *reinterpret_cast<const short8*>(
            &Bl[buf][tf * 16 + l15][ks * 32 + g * 8]);
        p = __builtin_amdgcn_mfma_f32_16x16x32_bf16(a[ks], bb, p, 0, 0, 0);
      }
      int t = t0 + tf * 16 + l15;
      bool valid = (t < T) && (mr[t < T ? t : 0] != 0);
#pragma unroll
      for (int r = 0; r < 4; r++) {
        float e = valid ? __expf(p[r]) : 0.f;  // logits tanh-bounded: no max-sub
        float xvf = bf2f((unsigned short)xv[buf][tf][r]);
        S0[r] += e; S1[r] += e * xvf; S2[r] += e * xvf * xvf;
      }
    }
    // refill xv[buf] for subtile k+2 (consumed at iter k+2; covered by iter k+1)
    if (k + 2 < ntt) GXV(buf, k + 2);
    __syncthreads();  // compute(k) done before buf gets overwritten at k+1
  }
#undef LOADSUB
#undef WRITESUB
#undef GXV

#pragma unroll
  for (int r = 0; r < 4; r++) {
#pragma unroll
    for (int o = 1; o < 16; o <<= 1) {
      S0[r] += __shfl_xor(S0[r], o, 16);
      S1[r] += __shfl_xor(S1[r], o, 16);
      S2[r] += __shfl_xor(S2[r], o, 16);
    }
  }
  if (l15 == 0) {
#pragma unroll
    for (int r = 0; r < 4; r++) {
      float* sp = &Sacc[((size_t)b * C + cbase + r) * 3];
      atomicAdd(sp, S0[r]);
      atomicAdd(sp + 1, S1[r]);
      atomicAdd(sp + 2, S2[r]);
    }
  }
}

// ---------------- K5: finalize pooled mean/std
__global__ __launch_bounds__(256) void k_out(
    const float* __restrict__ Sacc, float* __restrict__ out, int C) {
  int b = blockIdx.x;
  for (int c = threadIdx.x; c < C; c += 256) {
    float S0 = Sacc[((size_t)b * C + c) * 3];
    float S1 = Sacc[((size_t)b * C + c) * 3 + 1];
    float S2 = Sacc[((size_t)b * C + c) * 3 + 2];
    float pm = S1 / S0;
    float var = S2 / S0 - pm * pm;
    out[(size_t)b * 2 * C + c] = pm;
    out[(size_t)b * 2 * C + C + c] = sqrtf(fmaxf(var, EPSF));
  }
}

extern "C" void kernel_launch(void* const* d_in, const int* in_sizes, int n_in,
                              void* d_out, int out_size, void* d_ws, size_t ws_size,
                              hipStream_t stream) {
  const float* x = (const float*)d_in[0];
  const float* attn_w = (const float*)d_in[1];
  const float* attn_b = (const float*)d_in[2];
  const float* ctx_w = (const float*)d_in[3];
  const int* mask = (const int*)d_in[5];
  float* out = (float*)d_out;

  int D = in_sizes[2];         // 128
  int C = in_sizes[4];         // 512
  int B = out_size / (2 * C);  // 32
  int T = in_sizes[5] / B;     // 2000

  // workspace layout (~82.5 MB)
  unsigned short* awb = (unsigned short*)d_ws;        // D*C bf16
  unsigned short* cwb = awb + (size_t)D * C;          // C*D bf16
  float* bias2 = (float*)(cwb + (size_t)C * D);       // B*D
  float* Lbuf = bias2 + (size_t)B * D;                // B
  float* sums = Lbuf + B;                             // B*C*2 (zeroed)
  float* Sacc = sums + (size_t)B * C * 2;             // B*C*3 (zeroed)
  unsigned short* xbT = (unsigned short*)(Sacc + (size_t)B * C * 3);  // B*T*C bf16
  unsigned short* alphaT = xbT + (size_t)B * T * C;                   // B*T*D bf16

  int nz4 = (B * C * 5 + 3) / 4;  // sums + Sacc, in float4 units
  int zcn = 2 * D * C;
  if (nz4 > zcn) zcn = nz4;
  k_zc<<<(zcn + 255) / 256, 256, 0, stream>>>(
      attn_w, ctx_w, mask, awb, cwb, sums, Lbuf, nz4, C, D, B, T);
  k_ms_tr<<<dim3(C / 64, (T + 255) / 256, B), 256, 0, stream>>>(x, mask, sums, xbT, C, T);
  k_bias2f<<<B * (D / 4), 256, 0, stream>>>(attn_w, attn_b, sums, Lbuf, bias2, C, D);
  k_gemm1<<<dim3((T + 63) / 64, B), 256, 0, stream>>>(xbT, awb, bias2, alphaT, C, T, D);
  k_pool2<<<dim3((T + 511) / 512, C / 64, B), 256, 0, stream>>>(
      alphaT, cwb, xbT, mask, Sacc, C, T, D);
  k_out<<<B, 256, 0, stream>>>(Sacc, out, C);
}